// Round 2
// baseline (451.344 us; speedup 1.0000x reference)
//
#include <hip/hip_runtime.h>
#include <hip/hip_bf16.h>
#include <math.h>

#define NN 4096
#define IN_F 256
#define OUT_F 64
#define HEADS 4
#define EDGE_F 32
#define HO 256          // HEADS*OUT_F
#define ALPHA 0.2f

// ---------------- kernel 1: Wh = h @ W  (4096x256 @ 256x256) ----------------
__global__ __launch_bounds__(256) void k_wh(const float* __restrict__ h,
                                            const float* __restrict__ W,
                                            float* __restrict__ Wh) {
    __shared__ float hs[32][33];
    __shared__ float Ws[32][HO];
    const int n0 = blockIdx.x * 32;
    const int tid = threadIdx.x;
    float acc[32];
#pragma unroll
    for (int r = 0; r < 32; ++r) acc[r] = 0.f;
    for (int kc = 0; kc < IN_F; kc += 32) {
        for (int idx = tid; idx < 32 * 32; idx += 256) {
            int r = idx >> 5, k = idx & 31;
            hs[r][k] = h[(size_t)(n0 + r) * IN_F + kc + k];
        }
        for (int idx = tid; idx < 32 * HO / 4; idx += 256) {
            int k = idx >> 6, c4 = (idx & 63) << 2;
            *(float4*)&Ws[k][c4] = *(const float4*)&W[(size_t)(kc + k) * HO + c4];
        }
        __syncthreads();
#pragma unroll 4
        for (int k = 0; k < 32; ++k) {
            float wv = Ws[k][tid];
#pragma unroll
            for (int r = 0; r < 32; ++r) acc[r] = fmaf(hs[r][k], wv, acc[r]);
        }
        __syncthreads();
    }
    for (int r = 0; r < 32; ++r)
        Wh[(size_t)(n0 + r) * HO + tid] = acc[r];
}

// ---------------- kernel 2: src[n,h], c[n,h] = dst+edg (direct global reads) ----------------
__global__ __launch_bounds__(256) void k_coeffs(const float* __restrict__ Wh,
                                                const float* __restrict__ edge_attr,
                                                const float* __restrict__ a,
                                                float* __restrict__ src,
                                                float* __restrict__ cdp) {
    __shared__ float as[HEADS][2 * OUT_F + EDGE_F];
    const int n0 = blockIdx.x * 64;
    const int tid = threadIdx.x;
    for (int idx = tid; idx < HEADS * (2 * OUT_F + EDGE_F); idx += 256)
        ((float*)as)[idx] = a[idx];
    __syncthreads();
    const int nl = tid >> 2, hd = tid & 3;   // node-in-block, head
    const float* whrow = Wh + (size_t)(n0 + nl) * HO + hd * OUT_F;
    float s = 0.f, d = 0.f, eg = 0.f;
#pragma unroll
    for (int o4 = 0; o4 < OUT_F; o4 += 4) {
        const float4 w4 = *(const float4*)(whrow + o4);
        s = fmaf(w4.x, as[hd][o4 + 0], s);
        s = fmaf(w4.y, as[hd][o4 + 1], s);
        s = fmaf(w4.z, as[hd][o4 + 2], s);
        s = fmaf(w4.w, as[hd][o4 + 3], s);
        d = fmaf(w4.x, as[hd][OUT_F + o4 + 0], d);
        d = fmaf(w4.y, as[hd][OUT_F + o4 + 1], d);
        d = fmaf(w4.z, as[hd][OUT_F + o4 + 2], d);
        d = fmaf(w4.w, as[hd][OUT_F + o4 + 3], d);
    }
    const float* erow = edge_attr + (size_t)(n0 + nl) * EDGE_F;
#pragma unroll
    for (int e4 = 0; e4 < EDGE_F; e4 += 4) {
        const float4 ev = *(const float4*)(erow + e4);
        eg = fmaf(ev.x, as[hd][2 * OUT_F + e4 + 0], eg);
        eg = fmaf(ev.y, as[hd][2 * OUT_F + e4 + 1], eg);
        eg = fmaf(ev.z, as[hd][2 * OUT_F + e4 + 2], eg);
        eg = fmaf(ev.w, as[hd][2 * OUT_F + e4 + 3], eg);
    }
    src[(n0 + nl) * HEADS + hd] = s;
    cdp[(n0 + nl) * HEADS + hd] = d + eg;
}

// ---------------- kernel 3: per-row softmax stats m, L ----------------
__global__ __launch_bounds__(256) void k_stats(const int* __restrict__ adj,
                                               const float* __restrict__ src,
                                               const float* __restrict__ cdp,
                                               float* __restrict__ mrow,
                                               float* __restrict__ Lrow) {
    const int i = blockIdx.x;
    const int tid = threadIdx.x;
    const int lane = tid & 63, wid = tid >> 6;
    const float4 si = *(const float4*)(src + i * HEADS);
    const int* arow = adj + (size_t)i * NN;
    float4 mx = make_float4(-1e30f, -1e30f, -1e30f, -1e30f);
    for (int j = tid; j < NN; j += 256) {
        const int av = arow[j];
        const float4 c = *(const float4*)(cdp + j * HEADS);
        float e0 = si.x + c.x; e0 = e0 > 0.f ? e0 : ALPHA * e0; e0 = av > 0 ? e0 : 0.f;
        float e1 = si.y + c.y; e1 = e1 > 0.f ? e1 : ALPHA * e1; e1 = av > 0 ? e1 : 0.f;
        float e2 = si.z + c.z; e2 = e2 > 0.f ? e2 : ALPHA * e2; e2 = av > 0 ? e2 : 0.f;
        float e3 = si.w + c.w; e3 = e3 > 0.f ? e3 : ALPHA * e3; e3 = av > 0 ? e3 : 0.f;
        mx.x = fmaxf(mx.x, e0); mx.y = fmaxf(mx.y, e1);
        mx.z = fmaxf(mx.z, e2); mx.w = fmaxf(mx.w, e3);
    }
#pragma unroll
    for (int off = 32; off >= 1; off >>= 1) {
        mx.x = fmaxf(mx.x, __shfl_xor(mx.x, off));
        mx.y = fmaxf(mx.y, __shfl_xor(mx.y, off));
        mx.z = fmaxf(mx.z, __shfl_xor(mx.z, off));
        mx.w = fmaxf(mx.w, __shfl_xor(mx.w, off));
    }
    __shared__ float4 wred[4];
    if (lane == 0) wred[wid] = mx;
    __syncthreads();
    float4 m4;
    m4.x = fmaxf(fmaxf(wred[0].x, wred[1].x), fmaxf(wred[2].x, wred[3].x));
    m4.y = fmaxf(fmaxf(wred[0].y, wred[1].y), fmaxf(wred[2].y, wred[3].y));
    m4.z = fmaxf(fmaxf(wred[0].z, wred[1].z), fmaxf(wred[2].z, wred[3].z));
    m4.w = fmaxf(fmaxf(wred[0].w, wred[1].w), fmaxf(wred[2].w, wred[3].w));
    __syncthreads();
    float4 sm = make_float4(0.f, 0.f, 0.f, 0.f);
    for (int j = tid; j < NN; j += 256) {
        const int av = arow[j];
        const float4 c = *(const float4*)(cdp + j * HEADS);
        float e0 = si.x + c.x; e0 = e0 > 0.f ? e0 : ALPHA * e0; e0 = av > 0 ? e0 : 0.f;
        float e1 = si.y + c.y; e1 = e1 > 0.f ? e1 : ALPHA * e1; e1 = av > 0 ? e1 : 0.f;
        float e2 = si.z + c.z; e2 = e2 > 0.f ? e2 : ALPHA * e2; e2 = av > 0 ? e2 : 0.f;
        float e3 = si.w + c.w; e3 = e3 > 0.f ? e3 : ALPHA * e3; e3 = av > 0 ? e3 : 0.f;
        sm.x += __expf(e0 - m4.x); sm.y += __expf(e1 - m4.y);
        sm.z += __expf(e2 - m4.z); sm.w += __expf(e3 - m4.w);
    }
#pragma unroll
    for (int off = 32; off >= 1; off >>= 1) {
        sm.x += __shfl_xor(sm.x, off);
        sm.y += __shfl_xor(sm.y, off);
        sm.z += __shfl_xor(sm.z, off);
        sm.w += __shfl_xor(sm.w, off);
    }
    if (lane == 0) wred[wid] = sm;
    __syncthreads();
    if (tid == 0) {
        float4 L;
        L.x = wred[0].x + wred[1].x + wred[2].x + wred[3].x;
        L.y = wred[0].y + wred[1].y + wred[2].y + wred[3].y;
        L.z = wred[0].z + wred[1].z + wred[2].z + wred[3].z;
        L.w = wred[0].w + wred[1].w + wred[2].w + wred[3].w;
        *(float4*)(mrow + i * HEADS) = m4;
        *(float4*)(Lrow + i * HEADS) = L;
    }
}

// ---------------- kernel 4: PV (numerator), i-tile 64 x j-chunk 1024 ----------------
#define TI 64
#define TJ 32
#define JCHUNK 1024

__global__ __launch_bounds__(512) void k_pv(const int* __restrict__ adj,
                                            const float* __restrict__ Wh,
                                            const float* __restrict__ src,
                                            const float* __restrict__ cdp,
                                            const float* __restrict__ mrow,
                                            float* __restrict__ outAcc) {
    __shared__ __align__(16) float whs[TJ][HO];          // 32 KB
    __shared__ __align__(16) float ps[TI][TJ][HEADS];    // 32 KB
    const int ib = blockIdx.x & 63;
    const int jc = blockIdx.x >> 6;
    const int i0 = ib * TI;
    const int j0 = jc * JCHUNK;
    const int tid = threadIdx.x;
    const int lane = tid & 63;
    const int wid = tid >> 6;         // 0..7: row group (8 rows each)
    const int hl = lane >> 4;         // head for this lane's 4 columns
    float4 acc[8];
#pragma unroll
    for (int r = 0; r < 8; ++r) acc[r] = make_float4(0.f, 0.f, 0.f, 0.f);

    for (int jt = j0; jt < j0 + JCHUNK; jt += TJ) {
        // stage Wh tile: TJ x 256 floats
        for (int f = tid; f < TJ * HO / 4; f += 512) {
            int j = f >> 6, c4 = (f & 63) << 2;
            *(float4*)&whs[j][c4] = *(const float4*)&Wh[(size_t)(jt + j) * HO + c4];
        }
        // compute p tile: TI x TJ x 4
#pragma unroll
        for (int k = 0; k < 4; ++k) {
            const int pidx = k * 512 + tid;
            const int ii = pidx >> 5, jj = pidx & 31;
            const int av = adj[(size_t)(i0 + ii) * NN + jt + jj];
            const float4 c = *(const float4*)(cdp + (jt + jj) * HEADS);
            const float4 s4 = *(const float4*)(src + (i0 + ii) * HEADS);
            const float4 m4 = *(const float4*)(mrow + (i0 + ii) * HEADS);
            float4 p;
            float e;
            e = s4.x + c.x; e = e > 0.f ? e : ALPHA * e; e = av > 0 ? e : 0.f; p.x = __expf(e - m4.x);
            e = s4.y + c.y; e = e > 0.f ? e : ALPHA * e; e = av > 0 ? e : 0.f; p.y = __expf(e - m4.y);
            e = s4.z + c.z; e = e > 0.f ? e : ALPHA * e; e = av > 0 ? e : 0.f; p.z = __expf(e - m4.z);
            e = s4.w + c.w; e = e > 0.f ? e : ALPHA * e; e = av > 0 ? e : 0.f; p.w = __expf(e - m4.w);
            *(float4*)&ps[ii][jj][0] = p;
        }
        __syncthreads();
        const int rbase = wid << 3;
#pragma unroll 4
        for (int j = 0; j < TJ; ++j) {
            const float4 wv = *(const float4*)&whs[j][lane << 2];
#pragma unroll
            for (int r = 0; r < 8; ++r) {
                const float p = ps[rbase + r][j][hl];
                acc[r].x = fmaf(p, wv.x, acc[r].x);
                acc[r].y = fmaf(p, wv.y, acc[r].y);
                acc[r].z = fmaf(p, wv.z, acc[r].z);
                acc[r].w = fmaf(p, wv.w, acc[r].w);
            }
        }
        __syncthreads();
    }
    // accumulate partials (4 j-chunks) into zero-initialized d_out
    for (int r = 0; r < 8; ++r) {
        const int i = i0 + (wid << 3) + r;
        float* dst = outAcc + (size_t)i * HO + (lane << 2);
        atomicAdd(dst + 0, acc[r].x);
        atomicAdd(dst + 1, acc[r].y);
        atomicAdd(dst + 2, acc[r].z);
        atomicAdd(dst + 3, acc[r].w);
    }
}

// ---------------- kernel 5: divide by L, ELU ----------------
__global__ __launch_bounds__(256) void k_final(float* __restrict__ out,
                                               const float* __restrict__ Lrow) {
    const int idx = blockIdx.x * 256 + threadIdx.x;
    const int i = idx >> 8;
    const int c = idx & 255;
    const float L = Lrow[i * HEADS + (c >> 6)];
    const float x = out[idx] / L;
    out[idx] = x > 0.f ? x : (__expf(x) - 1.f);
}

extern "C" void kernel_launch(void* const* d_in, const int* in_sizes, int n_in,
                              void* d_out, int out_size, void* d_ws, size_t ws_size,
                              hipStream_t stream) {
    const float* h         = (const float*)d_in[0];
    const int*   adj       = (const int*)d_in[1];
    const float* edge_attr = (const float*)d_in[2];
    const float* W         = (const float*)d_in[3];
    const float* a         = (const float*)d_in[4];
    float* out = (float*)d_out;

    float* ws   = (float*)d_ws;
    float* Wh   = ws;                              // 4096*256
    float* src  = ws + (size_t)NN * HO;            // 4096*4
    float* cdp  = src + NN * HEADS;                // 4096*4
    float* mrow = cdp + NN * HEADS;                // 4096*4
    float* Lrow = mrow + NN * HEADS;               // 4096*4

    hipMemsetAsync(d_out, 0, (size_t)out_size * sizeof(float), stream);
    k_wh<<<NN / 32, 256, 0, stream>>>(h, W, Wh);
    k_coeffs<<<NN / 64, 256, 0, stream>>>(Wh, edge_attr, a, src, cdp);
    k_stats<<<NN, 256, 0, stream>>>(adj, src, cdp, mrow, Lrow);
    k_pv<<<256, 512, 0, stream>>>(adj, Wh, src, cdp, mrow, out);
    k_final<<<NN * HO / 256, 256, 0, stream>>>(out, Lrow);
}

// Round 3
// 248.527 us; speedup vs baseline: 1.8161x; 1.8161x over previous
//
#include <hip/hip_runtime.h>
#include <hip/hip_bf16.h>
#include <math.h>

#define NN 4096
#define IN_F 256
#define OUT_F 64
#define HEADS 4
#define EDGE_F 32
#define HO 256          // HEADS*OUT_F
#define ALPHA 0.2f

typedef __attribute__((ext_vector_type(8))) short bf16x8;
typedef __attribute__((ext_vector_type(4))) float f32x4;

__device__ __forceinline__ unsigned short f2bf(float x) {
    unsigned u = __float_as_uint(x);
    u += 0x7FFF + ((u >> 16) & 1);          // RNE
    return (unsigned short)(u >> 16);
}
__device__ __forceinline__ unsigned pack2(float lo, float hi) {
    return (unsigned)f2bf(lo) | ((unsigned)f2bf(hi) << 16);
}

// ---------------- kernel 1: Wh = h @ W ; also emit WhbT[c][j] bf16 ----------------
__global__ __launch_bounds__(256) void k_wh(const float* __restrict__ h,
                                            const float* __restrict__ W,
                                            float* __restrict__ Wh,
                                            unsigned short* __restrict__ WhbT) {
    __shared__ float hs[16][33];
    __shared__ float Ws[32][HO];
    const int n0 = blockIdx.x * 16;
    const int tid = threadIdx.x;
    float acc[16];
#pragma unroll
    for (int r = 0; r < 16; ++r) acc[r] = 0.f;
    for (int kc = 0; kc < IN_F; kc += 32) {
        for (int idx = tid; idx < 16 * 32; idx += 256) {
            int r = idx >> 5, k = idx & 31;
            hs[r][k] = h[(size_t)(n0 + r) * IN_F + kc + k];
        }
        for (int idx = tid; idx < 32 * HO / 4; idx += 256) {
            int k = idx >> 6, c4 = (idx & 63) << 2;
            *(float4*)&Ws[k][c4] = *(const float4*)&W[(size_t)(kc + k) * HO + c4];
        }
        __syncthreads();
#pragma unroll 8
        for (int k = 0; k < 32; ++k) {
            float wv = Ws[k][tid];
#pragma unroll
            for (int r = 0; r < 16; ++r) acc[r] = fmaf(hs[r][k], wv, acc[r]);
        }
        __syncthreads();
    }
#pragma unroll
    for (int r = 0; r < 16; ++r)
        Wh[(size_t)(n0 + r) * HO + tid] = acc[r];
    // transposed bf16 copy: column tid (= h*64+o), rows n0..n0+16
    unsigned* wb = (unsigned*)(WhbT + (size_t)tid * NN + n0);
#pragma unroll
    for (int t = 0; t < 8; ++t)
        wb[t] = pack2(acc[2 * t], acc[2 * t + 1]);
}

// ---------------- kernel 2: src[n,h]; cdpT[h][n] = dst+edg ----------------
__global__ __launch_bounds__(256) void k_coeffs(const float* __restrict__ Wh,
                                                const float* __restrict__ edge_attr,
                                                const float* __restrict__ a,
                                                float* __restrict__ src,
                                                float* __restrict__ cdpT) {
    __shared__ float as[HEADS][2 * OUT_F + EDGE_F];
    const int n0 = blockIdx.x * 64;
    const int tid = threadIdx.x;
    for (int idx = tid; idx < HEADS * (2 * OUT_F + EDGE_F); idx += 256)
        ((float*)as)[idx] = a[idx];
    __syncthreads();
    const int nl = tid >> 2, hd = tid & 3;   // node-in-block, head
    const float* whrow = Wh + (size_t)(n0 + nl) * HO + hd * OUT_F;
    float s = 0.f, d = 0.f, eg = 0.f;
#pragma unroll
    for (int o4 = 0; o4 < OUT_F; o4 += 4) {
        const float4 w4 = *(const float4*)(whrow + o4);
        s = fmaf(w4.x, as[hd][o4 + 0], s);
        s = fmaf(w4.y, as[hd][o4 + 1], s);
        s = fmaf(w4.z, as[hd][o4 + 2], s);
        s = fmaf(w4.w, as[hd][o4 + 3], s);
        d = fmaf(w4.x, as[hd][OUT_F + o4 + 0], d);
        d = fmaf(w4.y, as[hd][OUT_F + o4 + 1], d);
        d = fmaf(w4.z, as[hd][OUT_F + o4 + 2], d);
        d = fmaf(w4.w, as[hd][OUT_F + o4 + 3], d);
    }
    const float* erow = edge_attr + (size_t)(n0 + nl) * EDGE_F;
#pragma unroll
    for (int e4 = 0; e4 < EDGE_F; e4 += 4) {
        const float4 ev = *(const float4*)(erow + e4);
        eg = fmaf(ev.x, as[hd][2 * OUT_F + e4 + 0], eg);
        eg = fmaf(ev.y, as[hd][2 * OUT_F + e4 + 1], eg);
        eg = fmaf(ev.z, as[hd][2 * OUT_F + e4 + 2], eg);
        eg = fmaf(ev.w, as[hd][2 * OUT_F + e4 + 3], eg);
    }
    src[(n0 + nl) * HEADS + hd] = s;
    cdpT[(size_t)hd * NN + n0 + nl] = d + eg;
}

// ---------------- kernel 3: PV via MFMA, no max-shift, L accumulated ----------------
#define TI 32
#define JCH 1024

__global__ __launch_bounds__(512) void k_pv(const int* __restrict__ adj,
                                            const unsigned short* __restrict__ WhbT,
                                            const float* __restrict__ src,
                                            const float* __restrict__ cdpT,
                                            float* __restrict__ outAcc,
                                            float* __restrict__ Lrow) {
    const int tid = threadIdx.x;
    const int w = tid >> 6, l = tid & 63;
    const int hd = w & 3, mt = w >> 2;       // head, m-subtile
    const int ib = blockIdx.x & 127, jc = blockIdx.x >> 7;
    const int i0 = ib * TI, j0 = jc * JCH;
    const int lr = l & 15, kb = l >> 4;
    const int i = i0 + mt * 16 + lr;         // this lane's A-row
    const float si = src[i * HEADS + hd];

    const int* arow = adj + (size_t)i * NN + kb * 8;
    const float* crow = cdpT + (size_t)hd * NN + kb * 8;
    const unsigned short* wb0 = WhbT + (size_t)(hd * 64 +  0 + lr) * NN + kb * 8;
    const unsigned short* wb1 = WhbT + (size_t)(hd * 64 + 16 + lr) * NN + kb * 8;
    const unsigned short* wb2 = WhbT + (size_t)(hd * 64 + 32 + lr) * NN + kb * 8;
    const unsigned short* wb3 = WhbT + (size_t)(hd * 64 + 48 + lr) * NN + kb * 8;

    f32x4 acc0 = {0.f, 0.f, 0.f, 0.f};
    f32x4 acc1 = {0.f, 0.f, 0.f, 0.f};
    f32x4 acc2 = {0.f, 0.f, 0.f, 0.f};
    f32x4 acc3 = {0.f, 0.f, 0.f, 0.f};
    float Ls = 0.f;

    for (int jt = j0; jt < j0 + JCH; jt += 32) {
        const int4   a0 = *(const int4*)(arow + jt);
        const int4   a1 = *(const int4*)(arow + jt + 4);
        const float4 c0 = *(const float4*)(crow + jt);
        const float4 c1 = *(const float4*)(crow + jt + 4);
        float e, p0, p1, p2, p3, p4, p5, p6, p7;
        e = si + c0.x; e = fmaxf(e, ALPHA * e); e = a0.x > 0 ? e : 0.f; p0 = __expf(e);
        e = si + c0.y; e = fmaxf(e, ALPHA * e); e = a0.y > 0 ? e : 0.f; p1 = __expf(e);
        e = si + c0.z; e = fmaxf(e, ALPHA * e); e = a0.z > 0 ? e : 0.f; p2 = __expf(e);
        e = si + c0.w; e = fmaxf(e, ALPHA * e); e = a0.w > 0 ? e : 0.f; p3 = __expf(e);
        e = si + c1.x; e = fmaxf(e, ALPHA * e); e = a1.x > 0 ? e : 0.f; p4 = __expf(e);
        e = si + c1.y; e = fmaxf(e, ALPHA * e); e = a1.y > 0 ? e : 0.f; p5 = __expf(e);
        e = si + c1.z; e = fmaxf(e, ALPHA * e); e = a1.z > 0 ? e : 0.f; p6 = __expf(e);
        e = si + c1.w; e = fmaxf(e, ALPHA * e); e = a1.w > 0 ? e : 0.f; p7 = __expf(e);
        Ls += ((p0 + p1) + (p2 + p3)) + ((p4 + p5) + (p6 + p7));
        bf16x8 af;
        af[0] = (short)f2bf(p0); af[1] = (short)f2bf(p1);
        af[2] = (short)f2bf(p2); af[3] = (short)f2bf(p3);
        af[4] = (short)f2bf(p4); af[5] = (short)f2bf(p5);
        af[6] = (short)f2bf(p6); af[7] = (short)f2bf(p7);
        const bf16x8 b0 = *(const bf16x8*)(wb0 + jt);
        const bf16x8 b1 = *(const bf16x8*)(wb1 + jt);
        const bf16x8 b2 = *(const bf16x8*)(wb2 + jt);
        const bf16x8 b3 = *(const bf16x8*)(wb3 + jt);
        acc0 = __builtin_amdgcn_mfma_f32_16x16x32_bf16(af, b0, acc0, 0, 0, 0);
        acc1 = __builtin_amdgcn_mfma_f32_16x16x32_bf16(af, b1, acc1, 0, 0, 0);
        acc2 = __builtin_amdgcn_mfma_f32_16x16x32_bf16(af, b2, acc2, 0, 0, 0);
        acc3 = __builtin_amdgcn_mfma_f32_16x16x32_bf16(af, b3, acc3, 0, 0, 0);
    }

    // L: reduce across the 4 k-block lane groups (same row)
    Ls += __shfl_xor(Ls, 16);
    Ls += __shfl_xor(Ls, 32);
    if (l < 16) atomicAdd(Lrow + i * HEADS + hd, Ls);

    // numerator partials: C[row=(l>>4)*4+r][col=o0+lr]
#pragma unroll
    for (int r = 0; r < 4; ++r) {
        const int irow = i0 + mt * 16 + kb * 4 + r;
        float* dst = outAcc + (size_t)irow * HO + hd * 64 + lr;
        atomicAdd(dst +  0, acc0[r]);
        atomicAdd(dst + 16, acc1[r]);
        atomicAdd(dst + 32, acc2[r]);
        atomicAdd(dst + 48, acc3[r]);
    }
}

// ---------------- kernel 4: divide by L, ELU ----------------
__global__ __launch_bounds__(256) void k_final(float* __restrict__ out,
                                               const float* __restrict__ Lrow) {
    const int idx = blockIdx.x * 256 + threadIdx.x;
    const int i = idx >> 8;
    const int c = idx & 255;
    const float L = Lrow[i * HEADS + (c >> 6)];
    const float x = out[idx] / L;
    out[idx] = x > 0.f ? x : (__expf(x) - 1.f);
}

extern "C" void kernel_launch(void* const* d_in, const int* in_sizes, int n_in,
                              void* d_out, int out_size, void* d_ws, size_t ws_size,
                              hipStream_t stream) {
    const float* h         = (const float*)d_in[0];
    const int*   adj       = (const int*)d_in[1];
    const float* edge_attr = (const float*)d_in[2];
    const float* W         = (const float*)d_in[3];
    const float* a         = (const float*)d_in[4];
    float* out = (float*)d_out;

    float* ws = (float*)d_ws;
    float*          Wh    = ws;                                   // NN*HO floats (4 MB)
    unsigned short* WhbT  = (unsigned short*)(ws + (size_t)NN * HO); // NN*HO bf16 (2 MB)
    float*          cdpT  = ws + (size_t)NN * HO + (size_t)NN * HO / 2; // HEADS*NN
    float*          src   = cdpT + (size_t)HEADS * NN;            // NN*HEADS
    float*          Lrow  = src + (size_t)NN * HEADS;             // NN*HEADS

    hipMemsetAsync(d_out, 0, (size_t)out_size * sizeof(float), stream);
    hipMemsetAsync(Lrow, 0, (size_t)NN * HEADS * sizeof(float), stream);
    k_wh<<<NN / 16, 256, 0, stream>>>(h, W, Wh, WhbT);
    k_coeffs<<<NN / 64, 256, 0, stream>>>(Wh, edge_attr, a, src, cdpT);
    k_pv<<<512, 512, 0, stream>>>(adj, WhbT, src, cdpT, out, Lrow);
    k_final<<<NN * HO / 256, 256, 0, stream>>>(out, Lrow);
}

// Round 4
// 246.573 us; speedup vs baseline: 1.8305x; 1.0079x over previous
//
#include <hip/hip_runtime.h>
#include <hip/hip_bf16.h>
#include <math.h>

#define NN 4096
#define IN_F 256
#define OUT_F 64
#define HEADS 4
#define EDGE_F 32
#define HO 256          // HEADS*OUT_F
#define AVEC 160        // 2*OUT_F + EDGE_F
#define ALPHA 0.2f

typedef __attribute__((ext_vector_type(8))) short bf16x8;
typedef __attribute__((ext_vector_type(4))) float f32x4;

__device__ __forceinline__ unsigned short f2bf(float x) {
    unsigned u = __float_as_uint(x);
    u += 0x7FFF + ((u >> 16) & 1);          // RNE
    return (unsigned short)(u >> 16);
}
__device__ __forceinline__ unsigned pack2(float lo, float hi) {
    return (unsigned)f2bf(lo) | ((unsigned)f2bf(hi) << 16);
}

// ---- kernel 1: Wh GEMM (fp32 acc) -> WhbT bf16; fused coeffs (src, cdpT) ----
__global__ __launch_bounds__(256) void k_wh(const float* __restrict__ h,
                                            const float* __restrict__ W,
                                            const float* __restrict__ a,
                                            const float* __restrict__ edge_attr,
                                            unsigned short* __restrict__ WhbT,
                                            float* __restrict__ src,
                                            float* __restrict__ cdpT) {
    __shared__ float hs[16][33];
    __shared__ float Ws[32][HO];
    const int n0 = blockIdx.x * 16;
    const int tid = threadIdx.x;
    float acc[16];
#pragma unroll
    for (int r = 0; r < 16; ++r) acc[r] = 0.f;
    for (int kc = 0; kc < IN_F; kc += 32) {
        for (int idx = tid; idx < 16 * 32; idx += 256) {
            int r = idx >> 5, k = idx & 31;
            hs[r][k] = h[(size_t)(n0 + r) * IN_F + kc + k];
        }
        for (int idx = tid; idx < 32 * HO / 4; idx += 256) {
            int k = idx >> 6, c4 = (idx & 63) << 2;
            *(float4*)&Ws[k][c4] = *(const float4*)&W[(size_t)(kc + k) * HO + c4];
        }
        __syncthreads();
#pragma unroll 8
        for (int k = 0; k < 32; ++k) {
            float wv = Ws[k][tid];
#pragma unroll
            for (int r = 0; r < 16; ++r) acc[r] = fmaf(hs[r][k], wv, acc[r]);
        }
        __syncthreads();
    }
    // transposed bf16 output: column tid (= hd*64+o), rows n0..n0+15
    unsigned* wb = (unsigned*)(WhbT + (size_t)tid * NN + n0);
#pragma unroll
    for (int t = 0; t < 8; ++t)
        wb[t] = pack2(acc[2 * t], acc[2 * t + 1]);

    // fused coeffs: wave hd reduces over its 64 lanes (= the 64 out-features)
    const int hd = tid >> 6, lane = tid & 63;
    const float asrc = a[hd * AVEC + lane];
    const float adst = a[hd * AVEC + OUT_F + lane];
    float s_keep = 0.f, d_keep = 0.f;
#pragma unroll
    for (int r = 0; r < 16; ++r) {
        float sp = acc[r] * asrc;
        float dp = acc[r] * adst;
#pragma unroll
        for (int off = 32; off >= 1; off >>= 1) {
            sp += __shfl_xor(sp, off);
            dp += __shfl_xor(dp, off);
        }
        if (lane == r) { s_keep = sp; d_keep = dp; }
    }
    if (lane < 16) {
        float eg = 0.f;
        const float* erow = edge_attr + (size_t)(n0 + lane) * EDGE_F;
#pragma unroll
        for (int e4 = 0; e4 < EDGE_F; e4 += 4) {
            const float4 ev = *(const float4*)(erow + e4);
            eg = fmaf(ev.x, a[hd * AVEC + 2 * OUT_F + e4 + 0], eg);
            eg = fmaf(ev.y, a[hd * AVEC + 2 * OUT_F + e4 + 1], eg);
            eg = fmaf(ev.z, a[hd * AVEC + 2 * OUT_F + e4 + 2], eg);
            eg = fmaf(ev.w, a[hd * AVEC + 2 * OUT_F + e4 + 3], eg);
        }
        src[(n0 + lane) * HEADS + hd] = s_keep;
        cdpT[(size_t)hd * NN + n0 + lane] = d_keep + eg;
    }
}

// ---- kernel 2: PV via MFMA, software-pipelined, no max-shift, L accumulated ----
#define JCH 512

__global__ __launch_bounds__(256) void k_pv(const int* __restrict__ adj,
                                            const unsigned short* __restrict__ WhbT,
                                            const float* __restrict__ src,
                                            const float* __restrict__ cdpT,
                                            float* __restrict__ numAcc,
                                            float* __restrict__ Lrow) {
    const int tid = threadIdx.x;
    const int hd = tid >> 6, l = tid & 63;
    const int ib = blockIdx.x & 255, jc = blockIdx.x >> 8;
    const int i0 = ib * 16, j0 = jc * JCH;
    const int lr = l & 15, kb = l >> 4;
    const int i = i0 + lr;                   // this lane's A-row
    const float si = src[i * HEADS + hd];

    const int* arow = adj + (size_t)i * NN + kb * 8;
    const float* crow = cdpT + (size_t)hd * NN + kb * 8;
    const unsigned short* wb0 = WhbT + (size_t)(hd * 64 +  0 + lr) * NN + kb * 8;
    const unsigned short* wb1 = WhbT + (size_t)(hd * 64 + 16 + lr) * NN + kb * 8;
    const unsigned short* wb2 = WhbT + (size_t)(hd * 64 + 32 + lr) * NN + kb * 8;
    const unsigned short* wb3 = WhbT + (size_t)(hd * 64 + 48 + lr) * NN + kb * 8;

    f32x4 acc0 = {0.f, 0.f, 0.f, 0.f};
    f32x4 acc1 = {0.f, 0.f, 0.f, 0.f};
    f32x4 acc2 = {0.f, 0.f, 0.f, 0.f};
    f32x4 acc3 = {0.f, 0.f, 0.f, 0.f};
    float Ls = 0.f;

    // prologue: load iteration 0
    int4   a0 = *(const int4*)(arow + j0);
    int4   a1 = *(const int4*)(arow + j0 + 4);
    float4 c0 = *(const float4*)(crow + j0);
    float4 c1 = *(const float4*)(crow + j0 + 4);
    bf16x8 b0 = *(const bf16x8*)(wb0 + j0);
    bf16x8 b1 = *(const bf16x8*)(wb1 + j0);
    bf16x8 b2 = *(const bf16x8*)(wb2 + j0);
    bf16x8 b3 = *(const bf16x8*)(wb3 + j0);

    for (int jt = j0; jt < j0 + JCH; jt += 32) {
        // issue next iteration's loads (wrap on last iter; values unused)
        const int nj = (jt + 32 < j0 + JCH) ? jt + 32 : j0;
        const int4   na0 = *(const int4*)(arow + nj);
        const int4   na1 = *(const int4*)(arow + nj + 4);
        const float4 nc0 = *(const float4*)(crow + nj);
        const float4 nc1 = *(const float4*)(crow + nj + 4);
        const bf16x8 nb0 = *(const bf16x8*)(wb0 + nj);
        const bf16x8 nb1 = *(const bf16x8*)(wb1 + nj);
        const bf16x8 nb2 = *(const bf16x8*)(wb2 + nj);
        const bf16x8 nb3 = *(const bf16x8*)(wb3 + nj);

        float e, p0, p1, p2, p3, p4, p5, p6, p7;
        e = si + c0.x; e = fmaxf(e, ALPHA * e); e = a0.x > 0 ? e : 0.f; p0 = __expf(e);
        e = si + c0.y; e = fmaxf(e, ALPHA * e); e = a0.y > 0 ? e : 0.f; p1 = __expf(e);
        e = si + c0.z; e = fmaxf(e, ALPHA * e); e = a0.z > 0 ? e : 0.f; p2 = __expf(e);
        e = si + c0.w; e = fmaxf(e, ALPHA * e); e = a0.w > 0 ? e : 0.f; p3 = __expf(e);
        e = si + c1.x; e = fmaxf(e, ALPHA * e); e = a1.x > 0 ? e : 0.f; p4 = __expf(e);
        e = si + c1.y; e = fmaxf(e, ALPHA * e); e = a1.y > 0 ? e : 0.f; p5 = __expf(e);
        e = si + c1.z; e = fmaxf(e, ALPHA * e); e = a1.z > 0 ? e : 0.f; p6 = __expf(e);
        e = si + c1.w; e = fmaxf(e, ALPHA * e); e = a1.w > 0 ? e : 0.f; p7 = __expf(e);
        Ls += ((p0 + p1) + (p2 + p3)) + ((p4 + p5) + (p6 + p7));
        bf16x8 af;
        af[0] = (short)f2bf(p0); af[1] = (short)f2bf(p1);
        af[2] = (short)f2bf(p2); af[3] = (short)f2bf(p3);
        af[4] = (short)f2bf(p4); af[5] = (short)f2bf(p5);
        af[6] = (short)f2bf(p6); af[7] = (short)f2bf(p7);
        acc0 = __builtin_amdgcn_mfma_f32_16x16x32_bf16(af, b0, acc0, 0, 0, 0);
        acc1 = __builtin_amdgcn_mfma_f32_16x16x32_bf16(af, b1, acc1, 0, 0, 0);
        acc2 = __builtin_amdgcn_mfma_f32_16x16x32_bf16(af, b2, acc2, 0, 0, 0);
        acc3 = __builtin_amdgcn_mfma_f32_16x16x32_bf16(af, b3, acc3, 0, 0, 0);

        a0 = na0; a1 = na1; c0 = nc0; c1 = nc1;
        b0 = nb0; b1 = nb1; b2 = nb2; b3 = nb3;
    }

    // L: reduce across the 4 k-block lane groups (same row)
    Ls += __shfl_xor(Ls, 16);
    Ls += __shfl_xor(Ls, 32);
    if (l < 16) atomicAdd(Lrow + i * HEADS + hd, Ls);

    // numerator partials: C[row=kb*4+r][col=o-block+lr]
#pragma unroll
    for (int r = 0; r < 4; ++r) {
        const int irow = i0 + kb * 4 + r;
        float* dst = numAcc + (size_t)irow * HO + hd * 64 + lr;
        atomicAdd(dst +  0, acc0[r]);
        atomicAdd(dst + 16, acc1[r]);
        atomicAdd(dst + 32, acc2[r]);
        atomicAdd(dst + 48, acc3[r]);
    }
}

// ---- kernel 3: out = ELU(numAcc / L) ----
__global__ __launch_bounds__(256) void k_final(const float* __restrict__ numAcc,
                                               const float* __restrict__ Lrow,
                                               float* __restrict__ out) {
    const int idx = (blockIdx.x * 256 + threadIdx.x) * 4;
    const int i = idx >> 8;
    const int c = idx & 255;
    const float L = Lrow[i * HEADS + (c >> 6)];
    const float4 v = *(const float4*)(numAcc + idx);
    float4 o;
    float x;
    x = v.x / L; o.x = x > 0.f ? x : (__expf(x) - 1.f);
    x = v.y / L; o.y = x > 0.f ? x : (__expf(x) - 1.f);
    x = v.z / L; o.z = x > 0.f ? x : (__expf(x) - 1.f);
    x = v.w / L; o.w = x > 0.f ? x : (__expf(x) - 1.f);
    *(float4*)(out + idx) = o;
}

extern "C" void kernel_launch(void* const* d_in, const int* in_sizes, int n_in,
                              void* d_out, int out_size, void* d_ws, size_t ws_size,
                              hipStream_t stream) {
    const float* h         = (const float*)d_in[0];
    const int*   adj       = (const int*)d_in[1];
    const float* edge_attr = (const float*)d_in[2];
    const float* W         = (const float*)d_in[3];
    const float* a         = (const float*)d_in[4];
    float* out = (float*)d_out;

    float* ws = (float*)d_ws;
    float*          numAcc = ws;                                  // NN*HO f32 (4 MB)
    float*          Lrow   = numAcc + (size_t)NN * HO;            // NN*HEADS f32
    unsigned short* WhbT   = (unsigned short*)(Lrow + (size_t)NN * HEADS); // NN*HO bf16 (2 MB)
    float*          cdpT   = (float*)(WhbT + (size_t)NN * HO);    // HEADS*NN f32
    float*          src    = cdpT + (size_t)HEADS * NN;           // NN*HEADS f32

    // zero numAcc + Lrow in one shot (contiguous)
    hipMemsetAsync(numAcc, 0, ((size_t)NN * HO + NN * HEADS) * sizeof(float), stream);
    k_wh<<<NN / 16, 256, 0, stream>>>(h, W, a, edge_attr, WhbT, src, cdpT);
    k_pv<<<256 * 8, 256, 0, stream>>>(adj, WhbT, src, cdpT, numAcc, Lrow);
    k_final<<<NN * HO / 1024, 256, 0, stream>>>(numAcc, Lrow, out);
}

// Round 6
// 173.025 us; speedup vs baseline: 2.6085x; 1.4251x over previous
//
#include <hip/hip_runtime.h>
#include <hip/hip_bf16.h>
#include <math.h>

#define NN 4096
#define IN_F 256
#define OUT_F 64
#define HEADS 4
#define EDGE_F 32
#define HO 256          // HEADS*OUT_F
#define AVEC 160        // 2*OUT_F + EDGE_F
#define ALPHA 0.2f
#define LOG2E 1.44269504088896f

typedef __attribute__((ext_vector_type(8))) short bf16x8;
typedef __attribute__((ext_vector_type(4))) float f32x4;

__device__ __forceinline__ float exp2fast(float x) {
    return __builtin_amdgcn_exp2f(x);       // v_exp_f32: 2^x
}

__device__ __forceinline__ unsigned short f2bf(float x) {
    unsigned u = __float_as_uint(x);
    u += 0x7FFF + ((u >> 16) & 1);          // RNE
    return (unsigned short)(u >> 16);
}

// ---- kernel 1: adj -> transposed bit mask abitsT[j/32][i] (2 MB) ----
__global__ __launch_bounds__(256) void k_pack(const int* __restrict__ adj,
                                              unsigned* __restrict__ abitsT) {
    const int i = blockIdx.x;
    const int w = threadIdx.x >> 6, l = threadIdx.x & 63;
    const int* row = adj + (size_t)i * NN + w * 1024;
#pragma unroll
    for (int r = 0; r < 16; ++r) {
        const unsigned long long m = __ballot(row[r * 64 + l] > 0);
        const int jw = w * 32 + r * 2;
        if (l == 0) abitsT[(size_t)jw * NN + i] = (unsigned)m;
        else if (l == 1) abitsT[(size_t)(jw + 1) * NN + i] = (unsigned)(m >> 32);
    }
}

// ---- kernel 2: Wh GEMM -> pk (pre-packed bf16 B-fragments); fused coeffs ----
// block = (jb, hd): rows n0=jb*32, cols hd*64..+64. thread: rg=tid>>6 (wave), cl=tid&63.
// pk fragment layout: pk[((jblk*HEADS+hd)*4+g)*512 + lane*8 + e],
//   lane=kb*16+lr holds Whb[hd*64+g*16+lr][jblk*32+kb*8+e]  (B-frag of mfma_16x16x32_bf16)
__global__ __launch_bounds__(256) void k_wh(const float* __restrict__ h,
                                            const float* __restrict__ W,
                                            const float* __restrict__ a,
                                            const float* __restrict__ edge_attr,
                                            unsigned short* __restrict__ pk,
                                            float* __restrict__ src,
                                            float* __restrict__ cdpT) {
    __shared__ float hs[32][32];
    __shared__ float Ws[32][64];
    const int jb = blockIdx.x >> 2, hd = blockIdx.x & 3;
    const int n0 = jb * 32;
    const int tid = threadIdx.x;
    const int rg = tid >> 6, cl = tid & 63;
    float acc[8];
#pragma unroll
    for (int r = 0; r < 8; ++r) acc[r] = 0.f;

    for (int kc = 0; kc < IN_F; kc += 32) {
        {   // stage h tile: 32 rows x 32 k
            const int r = tid >> 3, k4 = (tid & 7) << 2;
            *(float4*)&hs[r][k4] = *(const float4*)&h[(size_t)(n0 + r) * IN_F + kc + k4];
        }
#pragma unroll
        for (int q = 0; q < 2; ++q) {   // stage W tile: 32 k x 64 c
            const int f = tid + q * 256;
            const int k = f >> 4, c4 = (f & 15) << 2;
            *(float4*)&Ws[k][c4] = *(const float4*)&W[(size_t)(kc + k) * HO + hd * 64 + c4];
        }
        __syncthreads();
#pragma unroll
        for (int k = 0; k < 32; ++k) {
            const float wv = Ws[k][cl];
#pragma unroll
            for (int r = 0; r < 8; ++r)
                acc[r] = fmaf(hs[rg * 8 + r][k], wv, acc[r]);
        }
        __syncthreads();
    }

    // pk store: one bf16x8 fragment per thread (kb = rg, e = r)
    {
        const int g = cl >> 4, lr = cl & 15;
        unsigned short* fb = pk + ((size_t)(jb * HEADS + hd) * 4 + g) * 512;
        bf16x8 v;
#pragma unroll
        for (int r = 0; r < 8; ++r) v[r] = (short)f2bf(acc[r]);
        *(bf16x8*)(fb + (rg * 16 + lr) * 8) = v;
    }

    // fused coeffs: this block's 64 cols ARE head hd's features -> full dots
    const float asrc = a[hd * AVEC + cl];
    const float adst = a[hd * AVEC + OUT_F + cl];
    float s_keep = 0.f, d_keep = 0.f;
#pragma unroll
    for (int r = 0; r < 8; ++r) {
        float sp = acc[r] * asrc;
        float dp = acc[r] * adst;
#pragma unroll
        for (int off = 32; off >= 1; off >>= 1) {
            sp += __shfl_xor(sp, off);
            dp += __shfl_xor(dp, off);
        }
        if (cl == r) { s_keep = sp; d_keep = dp; }
    }
    if (cl < 8) {
        const int i = n0 + rg * 8 + cl;
        float eg = 0.f;
        const float* erow = edge_attr + (size_t)i * EDGE_F;
#pragma unroll
        for (int e4 = 0; e4 < EDGE_F; e4 += 4) {
            const float4 ev = *(const float4*)(erow + e4);
            const float4 av = *(const float4*)(a + hd * AVEC + 2 * OUT_F + e4);
            eg = fmaf(ev.x, av.x, fmaf(ev.y, av.y, fmaf(ev.z, av.z, fmaf(ev.w, av.w, eg))));
        }
        src[i * HEADS + hd] = s_keep * LOG2E;                  // pre-scaled for exp2
        cdpT[(size_t)hd * NN + i] = (d_keep + eg) * LOG2E;
    }
}

// ---- kernel 3: PV via MFMA, full J per block, LDS cross-wave reduce, fused ELU ----
// block = (ib, hd): rows i0=ib*32, head hd. 8 waves: js = w&3 (j-slice), mt = w>>2 (m-tile).
__global__ __launch_bounds__(512, 4) void k_pv(const unsigned* __restrict__ abitsT,
                                               const unsigned short* __restrict__ pk,
                                               const float* __restrict__ src,
                                               const float* __restrict__ cdpT,
                                               float* __restrict__ out) {
    __shared__ float plds[4][32][65];   // [js][row][col] partial C
    __shared__ float lsum[4][32];       // [js][row] partial L
    const int tid = threadIdx.x;
    const int w = tid >> 6, l = tid & 63;
    const int js = w & 3, mt = w >> 2;
    const int ib = blockIdx.x >> 2, hd = blockIdx.x & 3;
    const int i0 = ib * 32;
    const int lr = l & 15, kb = l >> 4;
    const int i = i0 + mt * 16 + lr;                 // this lane's A-row
    const float si = src[i * HEADS + hd];
    const float* crow = cdpT + (size_t)hd * NN + kb * 8;
    const unsigned short* pkb = pk + (size_t)hd * 2048 + l * 8;

    f32x4 acc0 = {0.f, 0.f, 0.f, 0.f};
    f32x4 acc1 = {0.f, 0.f, 0.f, 0.f};
    f32x4 acc2 = {0.f, 0.f, 0.f, 0.f};
    f32x4 acc3 = {0.f, 0.f, 0.f, 0.f};
    float Ls = 0.f;

    for (int jt = js * 32; jt < NN; jt += 128) {
        const unsigned wbits = abitsT[(size_t)(jt >> 5) * NN + i];
        const unsigned byte = (wbits >> (kb * 8)) & 0xFFu;
        const float4 c0 = *(const float4*)(crow + jt);
        const float4 c1 = *(const float4*)(crow + jt + 4);
        const unsigned short* fb = pkb + (size_t)(jt >> 5) * (HEADS * 4 * 512);
        const bf16x8 b0 = *(const bf16x8*)(fb);
        const bf16x8 b1 = *(const bf16x8*)(fb + 512);
        const bf16x8 b2 = *(const bf16x8*)(fb + 1024);
        const bf16x8 b3 = *(const bf16x8*)(fb + 1536);
        float e, p0, p1, p2, p3, p4, p5, p6, p7;
        e = si + c0.x; e = fmaxf(e, ALPHA * e); e = (byte &   1u) ? e : 0.f; p0 = exp2fast(e);
        e = si + c0.y; e = fmaxf(e, ALPHA * e); e = (byte &   2u) ? e : 0.f; p1 = exp2fast(e);
        e = si + c0.z; e = fmaxf(e, ALPHA * e); e = (byte &   4u) ? e : 0.f; p2 = exp2fast(e);
        e = si + c0.w; e = fmaxf(e, ALPHA * e); e = (byte &   8u) ? e : 0.f; p3 = exp2fast(e);
        e = si + c1.x; e = fmaxf(e, ALPHA * e); e = (byte &  16u) ? e : 0.f; p4 = exp2fast(e);
        e = si + c1.y; e = fmaxf(e, ALPHA * e); e = (byte &  32u) ? e : 0.f; p5 = exp2fast(e);
        e = si + c1.z; e = fmaxf(e, ALPHA * e); e = (byte &  64u) ? e : 0.f; p6 = exp2fast(e);
        e = si + c1.w; e = fmaxf(e, ALPHA * e); e = (byte & 128u) ? e : 0.f; p7 = exp2fast(e);
        Ls += ((p0 + p1) + (p2 + p3)) + ((p4 + p5) + (p6 + p7));
        bf16x8 af;
        af[0] = (short)f2bf(p0); af[1] = (short)f2bf(p1);
        af[2] = (short)f2bf(p2); af[3] = (short)f2bf(p3);
        af[4] = (short)f2bf(p4); af[5] = (short)f2bf(p5);
        af[6] = (short)f2bf(p6); af[7] = (short)f2bf(p7);
        acc0 = __builtin_amdgcn_mfma_f32_16x16x32_bf16(af, b0, acc0, 0, 0, 0);
        acc1 = __builtin_amdgcn_mfma_f32_16x16x32_bf16(af, b1, acc1, 0, 0, 0);
        acc2 = __builtin_amdgcn_mfma_f32_16x16x32_bf16(af, b2, acc2, 0, 0, 0);
        acc3 = __builtin_amdgcn_mfma_f32_16x16x32_bf16(af, b3, acc3, 0, 0, 0);
    }

    // row-partial L for this js-slice: reduce over kb groups (same lr)
    Ls += __shfl_xor(Ls, 16);
    Ls += __shfl_xor(Ls, 32);
    if (l < 16) lsum[js][mt * 16 + lr] = Ls;
    // C partials: row = mt*16 + kb*4 + r, col = g*16 + lr
#pragma unroll
    for (int r = 0; r < 4; ++r) {
        const int row = mt * 16 + kb * 4 + r;
        plds[js][row][ 0 + lr] = acc0[r];
        plds[js][row][16 + lr] = acc1[r];
        plds[js][row][32 + lr] = acc2[r];
        plds[js][row][48 + lr] = acc3[r];
    }
    __syncthreads();

    // cross-wave reduce + divide + ELU + store (2048 elems, 4 per thread)
    const int row = tid >> 4, c4 = (tid & 15) << 2;
    const float L = lsum[0][row] + lsum[1][row] + lsum[2][row] + lsum[3][row];
    const float inv = 1.f / L;
    float4 o;
    float x;
    x = (plds[0][row][c4 + 0] + plds[1][row][c4 + 0] + plds[2][row][c4 + 0] + plds[3][row][c4 + 0]) * inv;
    o.x = x > 0.f ? x : (__expf(x) - 1.f);
    x = (plds[0][row][c4 + 1] + plds[1][row][c4 + 1] + plds[2][row][c4 + 1] + plds[3][row][c4 + 1]) * inv;
    o.y = x > 0.f ? x : (__expf(x) - 1.f);
    x = (plds[0][row][c4 + 2] + plds[1][row][c4 + 2] + plds[2][row][c4 + 2] + plds[3][row][c4 + 2]) * inv;
    o.z = x > 0.f ? x : (__expf(x) - 1.f);
    x = (plds[0][row][c4 + 3] + plds[1][row][c4 + 3] + plds[2][row][c4 + 3] + plds[3][row][c4 + 3]) * inv;
    o.w = x > 0.f ? x : (__expf(x) - 1.f);
    *(float4*)(out + (size_t)(i0 + row) * HO + hd * 64 + c4) = o;
}

extern "C" void kernel_launch(void* const* d_in, const int* in_sizes, int n_in,
                              void* d_out, int out_size, void* d_ws, size_t ws_size,
                              hipStream_t stream) {
    const float* h         = (const float*)d_in[0];
    const int*   adj       = (const int*)d_in[1];
    const float* edge_attr = (const float*)d_in[2];
    const float* W         = (const float*)d_in[3];
    const float* a         = (const float*)d_in[4];
    float* out = (float*)d_out;

    unsigned short* pk     = (unsigned short*)d_ws;                 // NN*HO bf16 (2 MB)
    float*          cdpT   = (float*)(pk + (size_t)NN * HO);        // HEADS*NN f32
    float*          src    = cdpT + (size_t)HEADS * NN;             // NN*HEADS f32
    unsigned*       abitsT = (unsigned*)(src + (size_t)NN * HEADS); // NN*NN/32 (2 MB)

    k_pack<<<NN, 256, 0, stream>>>(adj, abitsT);
    k_wh<<<128 * HEADS, 256, 0, stream>>>(h, W, a, edge_attr, pk, src, cdpT);
    k_pv<<<128 * HEADS, 512, 0, stream>>>(abitsT, pk, src, cdpT, out);
}